// Round 1
// baseline (1712.686 us; speedup 1.0000x reference)
//
#include <hip/hip_runtime.h>

#define IN_DIM 512
#define NBATCH 8192
#define BM 128
#define BN 128
#define BK 32
#define ASTR 40      // BK + 8 pad (bf16 elems) -> 80 B row stride, 16B aligned
#define HSTR 136     // BN + 8 pad -> 272 B row stride, 16B aligned

typedef short s16x8 __attribute__((ext_vector_type(8)));
typedef float f32x4 __attribute__((ext_vector_type(4)));

__device__ __forceinline__ unsigned short f2bf(float f) {
    union { float f; unsigned int u; } c;
    c.f = f;
    unsigned int u = c.u;
    u += 0x7fffu + ((u >> 16) & 1u);   // round-to-nearest-even
    return (unsigned short)(u >> 16);
}

// Fused per-net: h = relu(inp @ Wx_j + bx_j); logits = h @ Wp_j + bp_j;
// p = softmax(logits) * parent; write p to out columns [j*8 .. j*8+8).
__global__ __launch_bounds__(256, 2)
void level_kernel(const float* __restrict__ inp,
                  const float* __restrict__ Wx,
                  const float* __restrict__ bx,
                  const float* __restrict__ Wp,
                  const float* __restrict__ bp,
                  const float* __restrict__ parent,
                  int pstride, int poff, int invert_parent,
                  float* __restrict__ outp, int ostride)
{
    __shared__ __align__(16) unsigned short Ash[BM][ASTR];
    __shared__ __align__(16) unsigned short Bsh[BN][ASTR];
    __shared__ __align__(16) unsigned short Hsh[BM][HSTR];
    __shared__ __align__(16) unsigned short WpSh[8][IN_DIM];

    const int tid  = threadIdx.x;
    const int lane = tid & 63;
    const int wv   = tid >> 6;          // wave 0..3
    const int j    = blockIdx.y;        // net index
    const int rowBase = blockIdx.x * BM;
    const int lr = lane & 15;
    const int kg = (lane >> 4) * 8;
    const int rg = (lane >> 4) * 4;
    const int wm = (wv & 1) * 64;       // wave row offset in tile
    const int wn = (wv >> 1) * 64;      // wave col offset in tile

    const float* WxJ = Wx + (size_t)j * IN_DIM * IN_DIM;
    const float* WpJ = Wp + (size_t)j * IN_DIM * 8;

    // stage Wp^T into LDS: WpSh[w][k] (bf16), once per block
    for (int i = tid; i < IN_DIM * 2; i += 256) {
        int k  = i >> 1;
        int w4 = (i & 1) * 4;
        float4 v = *(const float4*)&WpJ[k * 8 + w4];
        WpSh[w4 + 0][k] = f2bf(v.x);
        WpSh[w4 + 1][k] = f2bf(v.y);
        WpSh[w4 + 2][k] = f2bf(v.z);
        WpSh[w4 + 3][k] = f2bf(v.w);
    }

    f32x4 acc2[2] = {};   // logits accumulator: wave rows [wv*32, wv*32+32)

    for (int nt = 0; nt < IN_DIM / BN; ++nt) {   // 4 column-tiles of the hidden dim
        f32x4 acc[4][4] = {};
        for (int k0 = 0; k0 < IN_DIM; k0 += BK) {
            __syncthreads();   // protect LDS before overwrite (also fences WpSh on first pass)
            // ---- stage A tile [BM][BK]: inp rows, convert f32->bf16 ----
            {
                int kk4 = (tid & 7) * 4;
                int rb  = tid >> 3;
                for (int it = 0; it < 4; ++it) {
                    int r = rb + it * 32;
                    float4 v = *(const float4*)&inp[(size_t)(rowBase + r) * IN_DIM + k0 + kk4];
                    unsigned short* dst = &Ash[r][kk4];
                    dst[0] = f2bf(v.x); dst[1] = f2bf(v.y);
                    dst[2] = f2bf(v.z); dst[3] = f2bf(v.w);
                }
            }
            // ---- stage B tile transposed: Bsh[n][k] from Wx[k][n] ----
            {
                int n4 = (tid & 31) * 4;
                int kb = tid >> 5;
                for (int it = 0; it < 4; ++it) {
                    int kk = kb + it * 8;
                    float4 v = *(const float4*)&WxJ[(size_t)(k0 + kk) * IN_DIM + nt * BN + n4];
                    Bsh[n4 + 0][kk] = f2bf(v.x);
                    Bsh[n4 + 1][kk] = f2bf(v.y);
                    Bsh[n4 + 2][kk] = f2bf(v.z);
                    Bsh[n4 + 3][kk] = f2bf(v.w);
                }
            }
            __syncthreads();
            // ---- MFMA: 4x4 fragments of 16x16, K=32 ----
            s16x8 af[4], bfr[4];
            for (int mt = 0; mt < 4; ++mt)
                af[mt] = *(const s16x8*)&Ash[wm + mt * 16 + lr][kg];
            for (int nn = 0; nn < 4; ++nn)
                bfr[nn] = *(const s16x8*)&Bsh[wn + nn * 16 + lr][kg];
            for (int mt = 0; mt < 4; ++mt)
                for (int nn = 0; nn < 4; ++nn)
                    acc[mt][nn] = __builtin_amdgcn_mfma_f32_16x16x32_bf16(
                        af[mt], bfr[nn], acc[mt][nn], 0, 0, 0);
        }
        __syncthreads();
        // ---- h = relu(acc + bx) -> Hsh (bf16) ----
        for (int nn = 0; nn < 4; ++nn) {
            int ncol = wn + nn * 16 + lr;
            float bxv = bx[(size_t)j * IN_DIM + nt * BN + ncol];
            for (int mt = 0; mt < 4; ++mt) {
                for (int v = 0; v < 4; ++v) {
                    float h = acc[mt][nn][v] + bxv;
                    h = h > 0.f ? h : 0.f;
                    Hsh[wm + mt * 16 + rg + v][ncol] = f2bf(h);
                }
            }
        }
        __syncthreads();
        // ---- stage-2: logits += Hsh @ Wp^T (N padded to 16; cols 8..15 zero) ----
        {
            s16x8 zero = {};
            for (int k2 = 0; k2 < BN; k2 += 32) {
                s16x8 b2 = (lr < 8) ? *(const s16x8*)&WpSh[lr][nt * BN + k2 + kg] : zero;
                for (int m2 = 0; m2 < 2; ++m2) {
                    s16x8 a2 = *(const s16x8*)&Hsh[wv * 32 + m2 * 16 + lr][k2 + kg];
                    acc2[m2] = __builtin_amdgcn_mfma_f32_16x16x32_bf16(
                        a2, b2, acc2[m2], 0, 0, 0);
                }
            }
        }
    }

    // ---- softmax over 8 cols (cross-lane, groups of 8) + parent scale + store ----
    bool valid = lr < 8;
    float bpv = valid ? bp[(size_t)j * 8 + lr] : 0.f;
    for (int m2 = 0; m2 < 2; ++m2) {
        for (int v = 0; v < 4; ++v) {
            float x = acc2[m2][v] + bpv;
            float mx = x;
            for (int d = 1; d < 8; d <<= 1)
                mx = fmaxf(mx, __shfl_xor(mx, d, 64));
            float e = __expf(x - mx);
            float s = e;
            for (int d = 1; d < 8; d <<= 1)
                s += __shfl_xor(s, d, 64);
            float p = e / s;
            int gb = rowBase + wv * 32 + m2 * 16 + rg + v;
            float pv = invert_parent ? (1.f - parent[(size_t)gb * pstride + poff])
                                     : parent[(size_t)gb * pstride + j];
            if (valid)
                outp[(size_t)gb * ostride + j * 8 + lr] = p * pv;
        }
    }
}

// got_event head: ge = sigmoid(inp @ We + be); write (1-ge) into the last
// column of all three output blocks. One wave per batch row.
__global__ __launch_bounds__(256)
void head_kernel(const float* __restrict__ inp,
                 const float* __restrict__ We,
                 const float* __restrict__ be,
                 float* __restrict__ out)
{
    int row  = blockIdx.x * 4 + (threadIdx.x >> 6);
    int lane = threadIdx.x & 63;
    const float* ip = inp + (size_t)row * IN_DIM;
    float4 a0 = *(const float4*)&ip[lane * 8];
    float4 a1 = *(const float4*)&ip[lane * 8 + 4];
    float4 w0 = *(const float4*)&We[lane * 8];
    float4 w1 = *(const float4*)&We[lane * 8 + 4];
    float s = a0.x*w0.x + a0.y*w0.y + a0.z*w0.z + a0.w*w0.w
            + a1.x*w1.x + a1.y*w1.y + a1.z*w1.z + a1.w*w1.w;
    for (int d = 1; d < 64; d <<= 1)
        s += __shfl_xor(s, d, 64);
    if (lane == 0) {
        float ge = 1.f / (1.f + __expf(-(s + be[0])));
        float og = 1.f - ge;
        out[(size_t)row * 9 + 8] = og;
        out[(size_t)(NBATCH * 9) + (size_t)row * 65 + 64] = og;
        out[(size_t)(NBATCH * 9 + NBATCH * 65) + (size_t)row * 513 + 512] = og;
    }
}

extern "C" void kernel_launch(void* const* d_in, const int* in_sizes, int n_in,
                              void* d_out, int out_size, void* d_ws, size_t ws_size,
                              hipStream_t stream) {
    const float* inp = (const float*)d_in[0];
    const float* Wx0 = (const float*)d_in[1];
    const float* bx0 = (const float*)d_in[2];
    const float* Wp0 = (const float*)d_in[3];
    const float* bp0 = (const float*)d_in[4];
    const float* Wx1 = (const float*)d_in[5];
    const float* bx1 = (const float*)d_in[6];
    const float* Wp1 = (const float*)d_in[7];
    const float* bp1 = (const float*)d_in[8];
    const float* Wx2 = (const float*)d_in[9];
    const float* bx2 = (const float*)d_in[10];
    const float* Wp2 = (const float*)d_in[11];
    const float* bp2 = (const float*)d_in[12];
    const float* We  = (const float*)d_in[13];
    const float* be  = (const float*)d_in[14];
    float* out = (float*)d_out;

    const size_t OUT1 = (size_t)NBATCH * 9;
    const size_t OUT2 = OUT1 + (size_t)NBATCH * 65;

    // head: fills last column of all three outputs (+ source for level0 parent)
    head_kernel<<<NBATCH / 4, 256, 0, stream>>>(inp, We, be, out);

    dim3 blk(256);
    // level 0: 1 net; parent = got_event = 1 - out0[:,8]
    level_kernel<<<dim3(NBATCH / BM, 1), blk, 0, stream>>>(
        inp, Wx0, bx0, Wp0, bp0,
        out, 9, 8, 1,
        out, 9);
    // level 1: 8 nets; parent = out0[:, j]
    level_kernel<<<dim3(NBATCH / BM, 8), blk, 0, stream>>>(
        inp, Wx1, bx1, Wp1, bp1,
        out, 9, 0, 0,
        out + OUT1, 65);
    // level 2: 64 nets; parent = out1[:, j]
    level_kernel<<<dim3(NBATCH / BM, 64), blk, 0, stream>>>(
        inp, Wx2, bx2, Wp2, bp2,
        out + OUT1, 65, 0, 0,
        out + OUT2, 513);
}

// Round 2
// 476.251 us; speedup vs baseline: 3.5962x; 3.5962x over previous
//
#include <hip/hip_runtime.h>

#define IN_DIM 512
#define NBATCH 8192
#define BM 128
#define BK 32
#define HSTR 136     // Hsh stride in u16: 272 B, 16B aligned, odd dword-multiple-ish to spread banks

typedef short s16x8 __attribute__((ext_vector_type(8)));
typedef float f32x4 __attribute__((ext_vector_type(4)));

__device__ __forceinline__ unsigned short f2bf(float f) {
    union { float f; unsigned int u; } c;
    c.f = f;
    unsigned int u = c.u;
    u += 0x7fffu + ((u >> 16) & 1u);   // round-to-nearest-even
    return (unsigned short)(u >> 16);
}

__device__ __forceinline__ void gload16(const unsigned short* g, unsigned short* l) {
    __builtin_amdgcn_global_load_lds(
        (const __attribute__((address_space(1))) void*)g,
        (__attribute__((address_space(3))) void*)l,
        16, 0, 0);
}

// ---------------- preprocessing: f32 -> bf16 (+ transpose for Wx, Wp) ----------------

__global__ __launch_bounds__(256)
void conv_inp(const float* __restrict__ in, unsigned short* __restrict__ out) {
    int i = (blockIdx.x * 256 + threadIdx.x) * 8;
    float4 a = *(const float4*)&in[i];
    float4 b = *(const float4*)&in[i + 4];
    union { unsigned short u[8]; s16x8 v; } r;
    r.u[0] = f2bf(a.x); r.u[1] = f2bf(a.y); r.u[2] = f2bf(a.z); r.u[3] = f2bf(a.w);
    r.u[4] = f2bf(b.x); r.u[5] = f2bf(b.y); r.u[6] = f2bf(b.z); r.u[7] = f2bf(b.w);
    *(s16x8*)&out[i] = r.v;
}

// WxT[j][col][k] = bf16(Wx[j][k][col]) via 64x64 LDS tile transpose
__global__ __launch_bounds__(256)
void conv_wxT(const float* __restrict__ Wx, unsigned short* __restrict__ WxT) {
    __shared__ unsigned short T[64][80];
    int j  = blockIdx.y;
    int tr = blockIdx.x >> 3;   // k-tile
    int tc = blockIdx.x & 7;    // col-tile
    const float* src = Wx + (size_t)j * IN_DIM * IN_DIM;
    unsigned short* dst = WxT + (size_t)j * IN_DIM * IN_DIM;
    int tid = threadIdx.x;
    int k  = tid >> 2;
    int c0 = (tid & 3) * 16;
    for (int u = 0; u < 16; u += 4) {
        float4 v = *(const float4*)&src[(size_t)(tr * 64 + k) * IN_DIM + tc * 64 + c0 + u];
        T[c0 + u + 0][k] = f2bf(v.x);
        T[c0 + u + 1][k] = f2bf(v.y);
        T[c0 + u + 2][k] = f2bf(v.z);
        T[c0 + u + 3][k] = f2bf(v.w);
    }
    __syncthreads();
    int c  = tid >> 2;
    int k0 = (tid & 3) * 16;
    for (int u = 0; u < 16; u += 8) {
        s16x8 v = *(const s16x8*)&T[c][k0 + u];
        *(s16x8*)&dst[(size_t)(tc * 64 + c) * IN_DIM + tr * 64 + k0 + u] = v;
    }
}

// WpT[j][w][k] = bf16(Wp[j][k][w])
__global__ __launch_bounds__(256)
void conv_wpT(const float* __restrict__ Wp, unsigned short* __restrict__ WpT) {
    int j = blockIdx.x;
    const float* src = Wp + (size_t)j * IN_DIM * 8;
    unsigned short* dst = WpT + (size_t)j * IN_DIM * 8;
    for (int k = threadIdx.x; k < IN_DIM; k += 256)
        for (int w = 0; w < 8; ++w)
            dst[w * IN_DIM + k] = f2bf(src[k * 8 + w]);
}

// ---------------- fast fused level kernel (bf16 weights preconverted) ----------------
// h = relu(inp @ Wx_j + bx); logits = h @ Wp_j + bp; p = softmax(logits)*parent
__global__ __launch_bounds__(256, 2)
void level_fast(const unsigned short* __restrict__ inpB,   // [8192][512] bf16
                const unsigned short* __restrict__ WxT,    // [n][512 col][512 k] bf16
                const float* __restrict__ bx,              // [n][512]
                const unsigned short* __restrict__ WpT,    // [n][8][512] bf16
                const float* __restrict__ bp,              // [n][8]
                const float* __restrict__ parent,
                int pstride, int poff, int invert_parent,
                float* __restrict__ outp, int ostride)
{
    // union: A [128][32] u16 @ [0,4096) ; B [128][32] u16 @ [4096,8192) ; Hsh [128][HSTR] @ [0,17408)
    __shared__ __align__(16) unsigned short lds[BM * HSTR];

    const int tid  = threadIdx.x;
    const int lane = tid & 63;
    const int wv   = tid >> 6;
    const int j    = blockIdx.y;
    const int rowBase = blockIdx.x * BM;
    const int lr  = lane & 15;
    const int kg8 = (lane >> 4) * 8;
    const int rg  = (lane >> 4) * 4;
    const int wm  = (wv & 1) * 64;
    const int wn  = (wv >> 1) * 64;

    const unsigned short* WxTj = WxT + (size_t)j * IN_DIM * IN_DIM;
    const unsigned short* WpTj = WpT + (size_t)j * IN_DIM * 8;

    // staging geometry: wave wv covers tile rows [wv*32, wv*32+32) in two 1KB issues
    const int srow  = wv * 32 + (lane >> 2);   // + 16 for second half
    const int sslot = (lane & 3) * 8;          // k elems

    f32x4 acc2[2] = {};

    for (int nt = 0; nt < 4; ++nt) {
        f32x4 acc[4][4] = {};
        for (int k0 = 0; k0 < IN_DIM; k0 += BK) {
            __syncthreads();   // previous LDS consumers done
            {
                const unsigned short* ga = inpB + (size_t)(rowBase + srow) * IN_DIM + k0 + sslot;
                const unsigned short* gb = WxTj + (size_t)(nt * BM + srow) * IN_DIM + k0 + sslot;
                gload16(ga,                &lds[wv * 1024]);
                gload16(ga + 16 * IN_DIM,  &lds[wv * 1024 + 512]);
                gload16(gb,                &lds[4096 + wv * 1024]);
                gload16(gb + 16 * IN_DIM,  &lds[4096 + wv * 1024 + 512]);
            }
            __syncthreads();   // compiler drains vmcnt before this barrier
            s16x8 af[4], bfr[4];
            for (int mt = 0; mt < 4; ++mt)
                af[mt] = *(const s16x8*)&lds[(wm + mt * 16 + lr) * 32 + kg8];
            for (int nn = 0; nn < 4; ++nn)
                bfr[nn] = *(const s16x8*)&lds[4096 + (wn + nn * 16 + lr) * 32 + kg8];
            for (int mt = 0; mt < 4; ++mt)
                for (int nn = 0; nn < 4; ++nn)
                    acc[mt][nn] = __builtin_amdgcn_mfma_f32_16x16x32_bf16(
                        af[mt], bfr[nn], acc[mt][nn], 0, 0, 0);
        }
        __syncthreads();   // stage-1 LDS reads done -> safe to overlay Hsh
        // h = relu(acc + bx) -> Hsh bf16
        for (int nn = 0; nn < 4; ++nn) {
            int ncol = wn + nn * 16 + lr;
            float bxv = bx[(size_t)j * IN_DIM + nt * BM + ncol];
            for (int mt = 0; mt < 4; ++mt)
                for (int v = 0; v < 4; ++v) {
                    float h = acc[mt][nn][v] + bxv;
                    h = h > 0.f ? h : 0.f;
                    lds[(wm + mt * 16 + rg + v) * HSTR + ncol] = f2bf(h);
                }
        }
        __syncthreads();
        // stage-2: logits += Hsh @ WpT (B-frags straight from global; cols 8-15 quarantined dupes)
        for (int k2 = 0; k2 < 4; ++k2) {
            int jw = lr & 7;
            s16x8 b2 = *(const s16x8*)(WpTj + jw * IN_DIM + nt * BM + k2 * 32 + kg8);
            for (int m2 = 0; m2 < 2; ++m2) {
                s16x8 a2 = *(const s16x8*)&lds[(wv * 32 + m2 * 16 + lr) * HSTR + k2 * 32 + kg8];
                acc2[m2] = __builtin_amdgcn_mfma_f32_16x16x32_bf16(a2, b2, acc2[m2], 0, 0, 0);
            }
        }
    }

    // softmax over 8 cols + parent scale + store
    bool valid = lr < 8;
    float bpv = valid ? bp[(size_t)j * 8 + lr] : 0.f;
    for (int m2 = 0; m2 < 2; ++m2) {
        for (int v = 0; v < 4; ++v) {
            float x = acc2[m2][v] + bpv;
            float mx = x;
            for (int d = 1; d < 8; d <<= 1)
                mx = fmaxf(mx, __shfl_xor(mx, d, 64));
            float e = __expf(x - mx);
            float s = e;
            for (int d = 1; d < 8; d <<= 1)
                s += __shfl_xor(s, d, 64);
            float p = e / s;
            int gb = rowBase + wv * 32 + m2 * 16 + rg + v;
            float pv = invert_parent ? (1.f - parent[(size_t)gb * pstride + poff])
                                     : parent[(size_t)gb * pstride + j];
            if (valid)
                outp[(size_t)gb * ostride + j * 8 + lr] = p * pv;
        }
    }
}

// ---------------- fallback (round-1) level kernel, used if ws too small ----------------
__global__ __launch_bounds__(256, 2)
void level_ref(const float* __restrict__ inp,
               const float* __restrict__ Wx,
               const float* __restrict__ bx,
               const float* __restrict__ Wp,
               const float* __restrict__ bp,
               const float* __restrict__ parent,
               int pstride, int poff, int invert_parent,
               float* __restrict__ outp, int ostride)
{
    __shared__ __align__(16) unsigned short Ash[128][40];
    __shared__ __align__(16) unsigned short Bsh[128][40];
    __shared__ __align__(16) unsigned short Hsh[128][HSTR];
    __shared__ __align__(16) unsigned short WpSh[8][IN_DIM];

    const int tid  = threadIdx.x;
    const int lane = tid & 63;
    const int wv   = tid >> 6;
    const int j    = blockIdx.y;
    const int rowBase = blockIdx.x * 128;
    const int lr = lane & 15;
    const int kg = (lane >> 4) * 8;
    const int rg = (lane >> 4) * 4;
    const int wm = (wv & 1) * 64;
    const int wn = (wv >> 1) * 64;

    const float* WxJ = Wx + (size_t)j * IN_DIM * IN_DIM;
    const float* WpJ = Wp + (size_t)j * IN_DIM * 8;

    for (int i = tid; i < IN_DIM * 2; i += 256) {
        int k  = i >> 1;
        int w4 = (i & 1) * 4;
        float4 v = *(const float4*)&WpJ[k * 8 + w4];
        WpSh[w4 + 0][k] = f2bf(v.x);
        WpSh[w4 + 1][k] = f2bf(v.y);
        WpSh[w4 + 2][k] = f2bf(v.z);
        WpSh[w4 + 3][k] = f2bf(v.w);
    }

    f32x4 acc2[2] = {};

    for (int nt = 0; nt < 4; ++nt) {
        f32x4 acc[4][4] = {};
        for (int k0 = 0; k0 < IN_DIM; k0 += 32) {
            __syncthreads();
            {
                int kk4 = (tid & 7) * 4;
                int rb  = tid >> 3;
                for (int it = 0; it < 4; ++it) {
                    int r = rb + it * 32;
                    float4 v = *(const float4*)&inp[(size_t)(rowBase + r) * IN_DIM + k0 + kk4];
                    unsigned short* dst = &Ash[r][kk4];
                    dst[0] = f2bf(v.x); dst[1] = f2bf(v.y);
                    dst[2] = f2bf(v.z); dst[3] = f2bf(v.w);
                }
            }
            {
                int n4 = (tid & 31) * 4;
                int kb = tid >> 5;
                for (int it = 0; it < 4; ++it) {
                    int kk = kb + it * 8;
                    float4 v = *(const float4*)&WxJ[(size_t)(k0 + kk) * IN_DIM + nt * 128 + n4];
                    Bsh[n4 + 0][kk] = f2bf(v.x);
                    Bsh[n4 + 1][kk] = f2bf(v.y);
                    Bsh[n4 + 2][kk] = f2bf(v.z);
                    Bsh[n4 + 3][kk] = f2bf(v.w);
                }
            }
            __syncthreads();
            s16x8 af[4], bfr[4];
            for (int mt = 0; mt < 4; ++mt)
                af[mt] = *(const s16x8*)&Ash[wm + mt * 16 + lr][kg];
            for (int nn = 0; nn < 4; ++nn)
                bfr[nn] = *(const s16x8*)&Bsh[wn + nn * 16 + lr][kg];
            for (int mt = 0; mt < 4; ++mt)
                for (int nn = 0; nn < 4; ++nn)
                    acc[mt][nn] = __builtin_amdgcn_mfma_f32_16x16x32_bf16(
                        af[mt], bfr[nn], acc[mt][nn], 0, 0, 0);
        }
        __syncthreads();
        for (int nn = 0; nn < 4; ++nn) {
            int ncol = wn + nn * 16 + lr;
            float bxv = bx[(size_t)j * IN_DIM + nt * 128 + ncol];
            for (int mt = 0; mt < 4; ++mt)
                for (int v = 0; v < 4; ++v) {
                    float h = acc[mt][nn][v] + bxv;
                    h = h > 0.f ? h : 0.f;
                    Hsh[wm + mt * 16 + rg + v][ncol] = f2bf(h);
                }
        }
        __syncthreads();
        {
            s16x8 zero = {};
            for (int k2 = 0; k2 < 128; k2 += 32) {
                s16x8 b2 = (lr < 8) ? *(const s16x8*)&WpSh[lr][nt * 128 + k2 + kg] : zero;
                for (int m2 = 0; m2 < 2; ++m2) {
                    s16x8 a2 = *(const s16x8*)&Hsh[wv * 32 + m2 * 16 + lr][k2 + kg];
                    acc2[m2] = __builtin_amdgcn_mfma_f32_16x16x32_bf16(a2, b2, acc2[m2], 0, 0, 0);
                }
            }
        }
    }

    bool valid = lr < 8;
    float bpv = valid ? bp[(size_t)j * 8 + lr] : 0.f;
    for (int m2 = 0; m2 < 2; ++m2) {
        for (int v = 0; v < 4; ++v) {
            float x = acc2[m2][v] + bpv;
            float mx = x;
            for (int d = 1; d < 8; d <<= 1)
                mx = fmaxf(mx, __shfl_xor(mx, d, 64));
            float e = __expf(x - mx);
            float s = e;
            for (int d = 1; d < 8; d <<= 1)
                s += __shfl_xor(s, d, 64);
            float p = e / s;
            int gb = rowBase + wv * 32 + m2 * 16 + rg + v;
            float pv = invert_parent ? (1.f - parent[(size_t)gb * pstride + poff])
                                     : parent[(size_t)gb * pstride + j];
            if (valid)
                outp[(size_t)gb * ostride + j * 8 + lr] = p * pv;
        }
    }
}

// got_event head
__global__ __launch_bounds__(256)
void head_kernel(const float* __restrict__ inp,
                 const float* __restrict__ We,
                 const float* __restrict__ be,
                 float* __restrict__ out)
{
    int row  = blockIdx.x * 4 + (threadIdx.x >> 6);
    int lane = threadIdx.x & 63;
    const float* ip = inp + (size_t)row * IN_DIM;
    float4 a0 = *(const float4*)&ip[lane * 8];
    float4 a1 = *(const float4*)&ip[lane * 8 + 4];
    float4 w0 = *(const float4*)&We[lane * 8];
    float4 w1 = *(const float4*)&We[lane * 8 + 4];
    float s = a0.x*w0.x + a0.y*w0.y + a0.z*w0.z + a0.w*w0.w
            + a1.x*w1.x + a1.y*w1.y + a1.z*w1.z + a1.w*w1.w;
    for (int d = 1; d < 64; d <<= 1)
        s += __shfl_xor(s, d, 64);
    if (lane == 0) {
        float ge = 1.f / (1.f + __expf(-(s + be[0])));
        float og = 1.f - ge;
        out[(size_t)row * 9 + 8] = og;
        out[(size_t)(NBATCH * 9) + (size_t)row * 65 + 64] = og;
        out[(size_t)(NBATCH * 9 + NBATCH * 65) + (size_t)row * 513 + 512] = og;
    }
}

extern "C" void kernel_launch(void* const* d_in, const int* in_sizes, int n_in,
                              void* d_out, int out_size, void* d_ws, size_t ws_size,
                              hipStream_t stream) {
    const float* inp = (const float*)d_in[0];
    const float* Wx0 = (const float*)d_in[1];
    const float* bx0 = (const float*)d_in[2];
    const float* Wp0 = (const float*)d_in[3];
    const float* bp0 = (const float*)d_in[4];
    const float* Wx1 = (const float*)d_in[5];
    const float* bx1 = (const float*)d_in[6];
    const float* Wp1 = (const float*)d_in[7];
    const float* bp1 = (const float*)d_in[8];
    const float* Wx2 = (const float*)d_in[9];
    const float* bx2 = (const float*)d_in[10];
    const float* Wp2 = (const float*)d_in[11];
    const float* bp2 = (const float*)d_in[12];
    const float* We  = (const float*)d_in[13];
    const float* be  = (const float*)d_in[14];
    float* out = (float*)d_out;

    const size_t OUT1 = (size_t)NBATCH * 9;
    const size_t OUT2 = OUT1 + (size_t)NBATCH * 65;

    const size_t INP_E = (size_t)NBATCH * IN_DIM;          // 4,194,304
    const size_t WX_E  = (size_t)IN_DIM * IN_DIM;          // 262,144 per net
    const size_t WP_E  = (size_t)IN_DIM * 8;               // 4,096 per net
    const size_t NEED  = 2 * (INP_E + 73 * WX_E + 73 * WP_E);  // 47,259,648 B

    head_kernel<<<NBATCH / 4, 256, 0, stream>>>(inp, We, be, out);

    dim3 blk(256);
    if (ws_size >= NEED) {
        unsigned short* inpB   = (unsigned short*)d_ws;
        unsigned short* WxTall = inpB + INP_E;
        unsigned short* WpTall = WxTall + 73 * WX_E;

        conv_inp<<<NBATCH * IN_DIM / (256 * 8), 256, 0, stream>>>(inp, inpB);
        conv_wxT<<<dim3(64, 1),  blk, 0, stream>>>(Wx0, WxTall);
        conv_wxT<<<dim3(64, 8),  blk, 0, stream>>>(Wx1, WxTall + 1 * WX_E);
        conv_wxT<<<dim3(64, 64), blk, 0, stream>>>(Wx2, WxTall + 9 * WX_E);
        conv_wpT<<<1,  blk, 0, stream>>>(Wp0, WpTall);
        conv_wpT<<<8,  blk, 0, stream>>>(Wp1, WpTall + 1 * WP_E);
        conv_wpT<<<64, blk, 0, stream>>>(Wp2, WpTall + 9 * WP_E);

        level_fast<<<dim3(NBATCH / BM, 1), blk, 0, stream>>>(
            inpB, WxTall, bx0, WpTall, bp0, out, 9, 8, 1, out, 9);
        level_fast<<<dim3(NBATCH / BM, 8), blk, 0, stream>>>(
            inpB, WxTall + 1 * WX_E, bx1, WpTall + 1 * WP_E, bp1,
            out, 9, 0, 0, out + OUT1, 65);
        level_fast<<<dim3(NBATCH / BM, 64), blk, 0, stream>>>(
            inpB, WxTall + 9 * WX_E, bx2, WpTall + 9 * WP_E, bp2,
            out + OUT1, 65, 0, 0, out + OUT2, 513);
    } else {
        level_ref<<<dim3(NBATCH / BM, 1), blk, 0, stream>>>(
            inp, Wx0, bx0, Wp0, bp0, out, 9, 8, 1, out, 9);
        level_ref<<<dim3(NBATCH / BM, 8), blk, 0, stream>>>(
            inp, Wx1, bx1, Wp1, bp1, out, 9, 0, 0, out + OUT1, 65);
        level_ref<<<dim3(NBATCH / BM, 64), blk, 0, stream>>>(
            inp, Wx2, bx2, Wp2, bp2, out + OUT1, 65, 0, 0, out + OUT2, 513);
    }
}